// Round 9
// baseline (747.197 us; speedup 1.0000x reference)
//
#include <hip/hip_runtime.h>

#define TT 256   // T
#define BB 512   // B
#define NG 256   // 4*H
#define KIN 128  // input width for both layers

typedef _Float16 half2v __attribute__((ext_vector_type(2)));
typedef _Float16 half4v __attribute__((ext_vector_type(4)));
typedef _Float16 half8v __attribute__((ext_vector_type(8)));
typedef float float4v __attribute__((ext_vector_type(4)));

__device__ __forceinline__ float sig_(float x){ return 1.f/(1.f+__expf(-x)); }
__device__ __forceinline__ float th_(float x){ return fmaf(2.f, 1.f/(1.f+__expf(-2.f*x)), -1.f); }

__device__ __forceinline__ half4v ld4h(const float* p){
  float4v v = *reinterpret_cast<const float4v*>(p);
  half4v h; h[0]=(_Float16)v[0]; h[1]=(_Float16)v[1]; h[2]=(_Float16)v[2]; h[3]=(_Float16)v[3];
  return h;
}

// ---- one-shot weight conversion fp32 -> fp16 into ws pool ----
// halves offsets: wih_l0f 0, wih_l0r 32768, wih_l1f 65536,
//                 whh_l0f 98304, whh_l0r 114688, whh_l1f 131072  (total 147456)
__global__ __launch_bounds__(256)
void conv_weights(const float* __restrict__ s0, const float* __restrict__ s1,
                  const float* __restrict__ s2, const float* __restrict__ s3,
                  const float* __restrict__ s4, const float* __restrict__ s5,
                  _Float16* __restrict__ dst)
{
  const int bid = blockIdx.x, tid = threadIdx.x;
  const float* src; int off, idx;
  if (bid < 128)      { src=s0; off=0;      idx=bid*256+tid; }
  else if (bid < 256) { src=s1; off=32768;  idx=(bid-128)*256+tid; }
  else if (bid < 384) { src=s2; off=65536;  idx=(bid-256)*256+tid; }
  else if (bid < 448) { src=s3; off=98304;  idx=(bid-384)*256+tid; }
  else if (bid < 512) { src=s4; off=114688; idx=(bid-448)*256+tid; }
  else                { src=s5; off=131072; idx=(bid-512)*256+tid; }
  dst[off+idx] = (_Float16)src[idx];
}

// C[m][n] = sum_k A[m][k]*W[n][k] + bias[n], written fp16.
template<typename AT>
__global__ __launch_bounds__(256)
void gemm_xg(const AT* __restrict__ A, const _Float16* __restrict__ W16,
             const float* __restrict__ bias, _Float16* __restrict__ Cout)
{
  __shared__ __align__(16) _Float16 aL[64][72];
  __shared__ __align__(16) _Float16 wL[256][72];
  const int tid  = threadIdx.x;
  const int wave = tid >> 6;
  const int lane = tid & 63;
  const int lr   = lane & 15;
  const int kg   = lane >> 4;
  const size_t m0 = (size_t)blockIdx.x * 64;

  float4v acc[4][4];
  #pragma unroll
  for (int a=0;a<4;a++)
    #pragma unroll
    for (int b=0;b<4;b++)
      acc[a][b] = float4v{0.f,0.f,0.f,0.f};

  for (int kc = 0; kc < KIN; kc += 64) {
    if constexpr (__is_same(AT, float)) {
      #pragma unroll
      for (int q=0;q<4;q++){
        int fi = tid + q*256;
        int r = fi >> 4, c4 = (fi & 15)*4;
        *reinterpret_cast<half4v*>(&aL[r][c4]) = ld4h(&A[(m0+(size_t)r)*KIN + kc + c4]);
      }
    } else {
      #pragma unroll
      for (int q=0;q<2;q++){
        int fi = tid + q*256;
        int r = fi >> 3, c8 = (fi & 7)*8;
        *reinterpret_cast<half8v*>(&aL[r][c8]) =
            *reinterpret_cast<const half8v*>(&A[(m0+(size_t)r)*KIN + kc + c8]);
      }
    }
    #pragma unroll
    for (int q=0;q<8;q++){
      int fi = tid + q*256;
      int n = fi >> 3, c8 = (fi & 7)*8;
      *reinterpret_cast<half8v*>(&wL[n][c8]) =
          *reinterpret_cast<const half8v*>(&W16[(size_t)n*KIN + kc + c8]);
    }
    __syncthreads();
    #pragma unroll
    for (int ks=0; ks<64; ks+=32){
      half8v af[4], bf[4];
      #pragma unroll
      for (int rt=0;rt<4;rt++)
        af[rt] = *reinterpret_cast<const half8v*>(&aL[rt*16+lr][ks + kg*8]);
      #pragma unroll
      for (int ct=0;ct<4;ct++)
        bf[ct] = *reinterpret_cast<const half8v*>(&wL[wave*64 + ct*16 + lr][ks + kg*8]);
      #pragma unroll
      for (int rt=0;rt<4;rt++)
        #pragma unroll
        for (int ct=0;ct<4;ct++)
          acc[rt][ct] = __builtin_amdgcn_mfma_f32_16x16x32_f16(af[rt], bf[ct], acc[rt][ct], 0,0,0);
    }
    __syncthreads();
  }
  #pragma unroll
  for (int ct=0;ct<4;ct++){
    const int col = wave*64 + ct*16 + lr;
    const float bv = bias[col];
    #pragma unroll
    for (int rt=0;rt<4;rt++){
      const size_t rbase = m0 + rt*16 + kg*4;
      #pragma unroll
      for (int i=0;i<4;i++)
        Cout[(rbase+(size_t)i)*NG + col] = (_Float16)(acc[rt][ct][i] + bv);
    }
  }
}

// ---------------- MFMA persistent-weight LSTM scan ----------------
// Block = 16 batch rows, 512 thr / 8 waves. Wave w: gate g=w>>1, col-half nh=w&1.
// Per step: gates[16][256] = xg[t] + h[16][64] @ whhT  via 16x16x32 f16 MFMA
// (2 n-tiles x 2 k-chunks per wave, B-frags persistent: 16 VGPRs/lane).
// h in XOR-swizzled LDS [16][64] fp16 (byte ^= (row&7)<<4); activations
// exchanged via acts[4][64][20] fp16 (stride-20 pad -> conflict-free b64).
// 2 barriers/step. xg: 8 scalar fp16 loads/lane/step, depth-2 named slots.
template<int MODE>
__global__ __launch_bounds__(512, 1)
void lstm_scan_mf(const _Float16* __restrict__ xgPool,   // fwd at 0, rev at +BB*TT*NG
                  const _Float16* __restrict__ whhPool,  // fwd at 0, rev at +16384
                  int nF,
                  _Float16* __restrict__ x1out, float* __restrict__ hfin)
{
  const int tid = threadIdx.x;
  const int w   = tid >> 6;          // wave 0..7
  const int l   = tid & 63;
  const int g   = w >> 1;            // gate 0..3 (i,f,g,o)
  const int nh  = w & 1;             // which 32-col half of the gate
  const int lr  = l & 15;
  const int kg  = l >> 4;
  const bool rev = (int)blockIdx.x >= nF;
  const int bblk = rev ? ((int)blockIdx.x - nF) : (int)blockIdx.x;
  const int b0 = bblk * 16;
  const _Float16* xg  = xgPool  + (rev ? (size_t)BB*TT*NG : 0);
  const _Float16* whh = whhPool + (rev ? (size_t)16384 : 0);

  __shared__ __align__(16) _Float16 h_lds[16*64];     // swizzled
  __shared__ __align__(16) _Float16 acts[4*64*20];    // [gate][col][16 rows + pad4]

  // B-frags: col = g*64 + nh*32 + ntl*16 + lr ; k = kc*32 + kg*8 (matches gemm_xg)
  const size_t colA = (size_t)g*64 + (size_t)nh*32 + (size_t)lr;
  half8v bf00 = *reinterpret_cast<const half8v*>(&whh[(colA   )*64 +  0 + kg*8]);
  half8v bf01 = *reinterpret_cast<const half8v*>(&whh[(colA   )*64 + 32 + kg*8]);
  half8v bf10 = *reinterpret_cast<const half8v*>(&whh[(colA+16)*64 +  0 + kg*8]);
  half8v bf11 = *reinterpret_cast<const half8v*>(&whh[(colA+16)*64 + 32 + kg*8]);
  asm volatile("" : "+v"(bf00), "+v"(bf01), "+v"(bf10), "+v"(bf11));

  // A-frag read offsets in h_lds (invariant): row=lr, halves kc*32+kg*8
  char* hb = (char*)h_lds;
  const int aswz  = (lr & 7) << 4;
  const int aoff0 = (lr*128 +  0 + kg*16) ^ aswz;
  const int aoff1 = (lr*128 + 64 + kg*16) ^ aswz;

  // acts write addrs (halves), phase A
  const int awr0 = (g*64 + nh*32 +  0 + lr)*20 + kg*4;
  const int awr1 = (g*64 + nh*32 + 16 + lr)*20 + kg*4;
  // acts read addrs (halves), phase B: rows 2w, 2w+1 at col l
  const int ard0 = (  0 + l)*20 + 2*w;
  const int ard1 = ( 64 + l)*20 + 2*w;
  const int ard2 = (128 + l)*20 + 2*w;
  const int ard3 = (192 + l)*20 + 2*w;
  // h write addrs (bytes, swizzled), phase B rows r0=2w, r1=2w+1
  const int r0 = 2*w, r1 = 2*w+1;
  const int hw0 = (r0*128 + l*2) ^ ((r0&7)<<4);
  const int hw1 = (r1*128 + l*2) ^ ((r1&7)<<4);

  // xg pointers: row kg*4+i, col g*64+nh*32+lr (+16 for ntl=1 via imm)
  const int t0 = rev ? (TT-1) : 0;
  const ptrdiff_t dstep = rev ? -(ptrdiff_t)NG : (ptrdiff_t)NG;
  const _Float16* p0 = xg + ((size_t)(b0 + kg*4 + 0)*TT + t0)*NG + colA;
  const _Float16* p1 = xg + ((size_t)(b0 + kg*4 + 1)*TT + t0)*NG + colA;
  const _Float16* p2 = xg + ((size_t)(b0 + kg*4 + 2)*TT + t0)*NG + colA;
  const _Float16* p3 = xg + ((size_t)(b0 + kg*4 + 3)*TT + t0)*NG + colA;

  half8v sA, sB;
  sA[0]=p0[0];  sA[1]=p1[0];  sA[2]=p2[0];  sA[3]=p3[0];
  sA[4]=p0[16]; sA[5]=p1[16]; sA[6]=p2[16]; sA[7]=p3[16];
  p0+=dstep; p1+=dstep; p2+=dstep; p3+=dstep;
  sB[0]=p0[0];  sB[1]=p1[0];  sB[2]=p2[0];  sB[3]=p3[0];
  sB[4]=p0[16]; sB[5]=p1[16]; sB[6]=p2[16]; sB[7]=p3[16];
  p0+=dstep; p1+=dstep; p2+=dstep; p3+=dstep;

  ((unsigned*)h_lds)[tid] = 0u;        // 512 u32 = whole 2KB tile
  float c0 = 0.f, c1 = 0.f, hl0 = 0.f, hl1 = 0.f;
  __syncthreads();

#define SCAN_STEP(tt_, S_) do {                                              \
    const int tt = (tt_);                                                    \
    const int t  = rev ? (TT-1-tt) : tt;                                     \
    half8v a0 = *reinterpret_cast<const half8v*>(hb + aoff0);                \
    half8v a1 = *reinterpret_cast<const half8v*>(hb + aoff1);                \
    float4v ac0, ac1;                                                        \
    ac0[0]=(float)S_[0]; ac0[1]=(float)S_[1];                                \
    ac0[2]=(float)S_[2]; ac0[3]=(float)S_[3];                                \
    ac1[0]=(float)S_[4]; ac1[1]=(float)S_[5];                                \
    ac1[2]=(float)S_[6]; ac1[3]=(float)S_[7];                                \
    if (tt+2 < TT){                                                          \
      S_[0]=p0[0];  S_[1]=p1[0];  S_[2]=p2[0];  S_[3]=p3[0];                 \
      S_[4]=p0[16]; S_[5]=p1[16]; S_[6]=p2[16]; S_[7]=p3[16];                \
      p0+=dstep; p1+=dstep; p2+=dstep; p3+=dstep;                            \
    }                                                                        \
    ac0 = __builtin_amdgcn_mfma_f32_16x16x32_f16(a0, bf00, ac0, 0,0,0);      \
    ac0 = __builtin_amdgcn_mfma_f32_16x16x32_f16(a1, bf01, ac0, 0,0,0);      \
    ac1 = __builtin_amdgcn_mfma_f32_16x16x32_f16(a0, bf10, ac1, 0,0,0);      \
    ac1 = __builtin_amdgcn_mfma_f32_16x16x32_f16(a1, bf11, ac1, 0,0,0);      \
    half4v pk0, pk1;                                                         \
    if (g == 2){                                                             \
      pk0[0]=(_Float16)th_(ac0[0]); pk0[1]=(_Float16)th_(ac0[1]);            \
      pk0[2]=(_Float16)th_(ac0[2]); pk0[3]=(_Float16)th_(ac0[3]);            \
      pk1[0]=(_Float16)th_(ac1[0]); pk1[1]=(_Float16)th_(ac1[1]);            \
      pk1[2]=(_Float16)th_(ac1[2]); pk1[3]=(_Float16)th_(ac1[3]);            \
    } else {                                                                 \
      pk0[0]=(_Float16)sig_(ac0[0]); pk0[1]=(_Float16)sig_(ac0[1]);          \
      pk0[2]=(_Float16)sig_(ac0[2]); pk0[3]=(_Float16)sig_(ac0[3]);          \
      pk1[0]=(_Float16)sig_(ac1[0]); pk1[1]=(_Float16)sig_(ac1[1]);          \
      pk1[2]=(_Float16)sig_(ac1[2]); pk1[3]=(_Float16)sig_(ac1[3]);          \
    }                                                                        \
    *reinterpret_cast<half4v*>(&acts[awr0]) = pk0;                           \
    *reinterpret_cast<half4v*>(&acts[awr1]) = pk1;                           \
    __syncthreads();                                                         \
    const half2v vi = *reinterpret_cast<const half2v*>(&acts[ard0]);         \
    const half2v vf = *reinterpret_cast<const half2v*>(&acts[ard1]);         \
    const half2v vg = *reinterpret_cast<const half2v*>(&acts[ard2]);         \
    const half2v vo = *reinterpret_cast<const half2v*>(&acts[ard3]);         \
    c0 = (float)vf[0]*c0 + (float)vi[0]*(float)vg[0];                        \
    c1 = (float)vf[1]*c1 + (float)vi[1]*(float)vg[1];                        \
    const float h0 = (float)vo[0]*th_(c0);                                   \
    const float h1 = (float)vo[1]*th_(c1);                                   \
    *reinterpret_cast<_Float16*>(hb + hw0) = (_Float16)h0;                   \
    *reinterpret_cast<_Float16*>(hb + hw1) = (_Float16)h1;                   \
    if constexpr (MODE==0){                                                  \
      const int xoff = rev ? 64 : 0;                                         \
      x1out[((size_t)(b0+r0)*TT + t)*128 + xoff + l] = (_Float16)h0;         \
      x1out[((size_t)(b0+r1)*TT + t)*128 + xoff + l] = (_Float16)h1;         \
    } else { hl0 = h0; hl1 = h1; }                                           \
    __syncthreads();                                                         \
  } while(0)

  for (int tb=0; tb<TT; tb+=2){
    SCAN_STEP(tb,   sA);
    SCAN_STEP(tb+1, sB);
  }
#undef SCAN_STEP

  if constexpr (MODE==1){
    hfin[(size_t)(b0+r0)*64 + l] = hl0;
    hfin[(size_t)(b0+r1)*64 + l] = hl1;
  }
}

// Layer-1 reverse collapses to ONE step from zero state on x1[:,T-1]; fuse with FC.
__global__ __launch_bounds__(256)
void final_fuse(const _Float16* __restrict__ x1, const float* __restrict__ w_ih,
                const float* __restrict__ bvec, const float* __restrict__ hfin,
                const float* __restrict__ fcw, const float* __restrict__ fcb,
                float* __restrict__ out)
{
  const int b = blockIdx.x, tid = threadIdx.x;
  __shared__ float xs[128];
  __shared__ float act[256];
  __shared__ float hall[128];
  if (tid < 128) xs[tid] = (float)x1[((size_t)b*TT + (TT-1))*128 + tid];
  __syncthreads();
  float a = bvec[tid];
  #pragma unroll
  for (int kk=0;kk<32;kk++){
    float4v wv = *reinterpret_cast<const float4v*>(&w_ih[(size_t)tid*128 + kk*4]);
    a += wv[0]*xs[kk*4] + wv[1]*xs[kk*4+1] + wv[2]*xs[kk*4+2] + wv[3]*xs[kk*4+3];
  }
  const int grp = tid>>6;
  act[tid] = (grp==2) ? th_(a) : sig_(a);
  __syncthreads();
  if (tid < 64) {
    float c = act[tid]*act[128+tid];        // c = i*g (c0 = 0)
    float h = act[192+tid]*th_(c);          // h = o*tanh(c)
    hall[64+tid] = h;
    hall[tid] = hfin[(size_t)b*64 + tid];
  }
  __syncthreads();
  if (tid < 3) {
    float acc2 = fcb[tid];
    for (int k=0;k<128;k++) acc2 += fcw[(size_t)tid*128 + k]*hall[k];
    out[(size_t)b*3 + tid] = acc2;
  }
}

extern "C" void kernel_launch(void* const* d_in, const int* in_sizes, int n_in,
                              void* d_out, int out_size, void* d_ws, size_t ws_size,
                              hipStream_t stream) {
  const float* x        = (const float*)d_in[0];
  const float* w_ih_l0f = (const float*)d_in[1];
  const float* w_hh_l0f = (const float*)d_in[2];
  const float* b_l0f    = (const float*)d_in[3];
  const float* w_ih_l0r = (const float*)d_in[4];
  const float* w_hh_l0r = (const float*)d_in[5];
  const float* b_l0r    = (const float*)d_in[6];
  const float* w_ih_l1f = (const float*)d_in[7];
  const float* w_hh_l1f = (const float*)d_in[8];
  const float* b_l1f    = (const float*)d_in[9];
  const float* w_ih_l1r = (const float*)d_in[10];
  const float* b_l1r    = (const float*)d_in[12];
  const float* fc_w     = (const float*)d_in[13];
  const float* fc_b     = (const float*)d_in[14];
  float* out = (float*)d_out;

  // workspace layout (bytes)
  const size_t XG_BYTES = (size_t)BB*TT*NG*2;      // 67,108,864 (fp16); xgF then xgR ADJACENT
  const size_t X1_BYTES = (size_t)BB*TT*128*2;     // 33,554,432
  const size_t HF_BYTES = (size_t)BB*64*4;         //    131,072
  const size_t W16_BYTES = (size_t)147456*2;       //    294,912
  if (ws_size < 2*XG_BYTES + X1_BYTES + HF_BYTES + W16_BYTES) return;
  _Float16* xgF  = (_Float16*)d_ws;
  _Float16* xgR  = (_Float16*)((char*)d_ws + XG_BYTES);   // = xgF + BB*TT*NG halves
  _Float16* x1   = (_Float16*)((char*)d_ws + 2*XG_BYTES);
  float*    hfin = (float*)   ((char*)d_ws + 2*XG_BYTES + X1_BYTES);
  _Float16* w16  = (_Float16*)((char*)d_ws + 2*XG_BYTES + X1_BYTES + HF_BYTES);
  _Float16* wih_l0f16 = w16;
  _Float16* wih_l0r16 = w16 + 32768;
  _Float16* wih_l1f16 = w16 + 65536;
  _Float16* whh_l0f16 = w16 + 98304;    // whh_l0r16 = +16384 halves (adjacent)
  _Float16* whh_l1f16 = w16 + 131072;

  const int MBLK = (BB*TT)/64;  // 2048

  conv_weights<<<576, 256, 0, stream>>>(w_ih_l0f, w_ih_l0r, w_ih_l1f,
                                        w_hh_l0f, w_hh_l0r, w_hh_l1f, w16);
  // layer 0: both input GEMMs, then fused fwd+rev MFMA scan (64 blocks x 512 thr)
  gemm_xg<float><<<MBLK, 256, 0, stream>>>(x, wih_l0f16, b_l0f, xgF);
  gemm_xg<float><<<MBLK, 256, 0, stream>>>(x, wih_l0r16, b_l0r, xgR);
  lstm_scan_mf<0><<<64, 512, 0, stream>>>(xgF, whh_l0f16, 32, x1, nullptr);
  // layer 1 forward (only final h needed): 32 blocks
  gemm_xg<_Float16><<<MBLK, 256, 0, stream>>>(x1, wih_l1f16, b_l1f, xgF);
  lstm_scan_mf<1><<<32, 512, 0, stream>>>(xgF, whh_l1f16, 32, nullptr, hfin);
  // layer 1 reverse one-step + FC
  final_fuse<<<BB, 256, 0, stream>>>(x1, w_ih_l1r, b_l1r, hfin, fc_w, fc_b, out);
}

// Round 10
// 697.283 us; speedup vs baseline: 1.0716x; 1.0716x over previous
//
#include <hip/hip_runtime.h>

#define TT 256   // T
#define BB 512   // B
#define NG 256   // 4*H
#define KIN 128  // input width for both layers

typedef _Float16 half2v __attribute__((ext_vector_type(2)));
typedef _Float16 half4v __attribute__((ext_vector_type(4)));
typedef _Float16 half8v __attribute__((ext_vector_type(8)));
typedef float float4v __attribute__((ext_vector_type(4)));

__device__ __forceinline__ float sig_(float x){ return 1.f/(1.f+__expf(-x)); }
__device__ __forceinline__ float th_(float x){ return fmaf(2.f, 1.f/(1.f+__expf(-2.f*x)), -1.f); }

#define SV2(v,k) __builtin_shufflevector((v),(v), 2*(k), 2*(k)+1)

#if __has_builtin(__builtin_elementwise_fma)
__device__ __forceinline__ half2v pkfma_(half2v a, half2v b, half2v c){
  return __builtin_elementwise_fma(a, b, c);
}
#else
__device__ __forceinline__ half2v pkfma_(half2v a, half2v b, half2v c){
  return a*b + c;   // ffp-contract=fast -> v_pk_fma_f16
}
#endif

__device__ __forceinline__ half4v ld4h(const float* p){
  float4v v = *reinterpret_cast<const float4v*>(p);
  half4v h; h[0]=(_Float16)v[0]; h[1]=(_Float16)v[1]; h[2]=(_Float16)v[2]; h[3]=(_Float16)v[3];
  return h;
}

// ---- one-shot weight conversion fp32 -> fp16 into ws pool ----
// halves offsets: wih_l0f 0, wih_l0r 32768, wih_l1f 65536  (row-major, for GEMM)
// whh_l0f 98304, whh_l0r 114688, whh_l1f 131072 (TRANSPOSED [kk][col] half8-unit)
__global__ __launch_bounds__(256)
void conv_weights(const float* __restrict__ s0, const float* __restrict__ s1,
                  const float* __restrict__ s2, const float* __restrict__ s3,
                  const float* __restrict__ s4, const float* __restrict__ s5,
                  _Float16* __restrict__ dst)
{
  const int bid = blockIdx.x, tid = threadIdx.x;
  const float* src; int off, idx; bool tr = false;
  if (bid < 128)      { src=s0; off=0;      idx=bid*256+tid; }
  else if (bid < 256) { src=s1; off=32768;  idx=(bid-128)*256+tid; }
  else if (bid < 384) { src=s2; off=65536;  idx=(bid-256)*256+tid; }
  else if (bid < 448) { src=s3; off=98304;  idx=(bid-384)*256+tid; tr=true; }
  else if (bid < 512) { src=s4; off=114688; idx=(bid-448)*256+tid; tr=true; }
  else                { src=s5; off=131072; idx=(bid-512)*256+tid; tr=true; }
  if (!tr){
    dst[off+idx] = (_Float16)src[idx];
  } else {
    // src [col][64] -> dst unit layout (kk*256+col)*8+e
    const int col = idx >> 6, k = idx & 63;
    const int kk = k >> 3, e = k & 7;
    dst[off + (kk*256 + col)*8 + e] = (_Float16)src[idx];
  }
}

// C[m][n] = sum_k A[m][k]*W[n][k] + bias[n], written fp16.
template<typename AT>
__global__ __launch_bounds__(256)
void gemm_xg(const AT* __restrict__ A, const _Float16* __restrict__ W16,
             const float* __restrict__ bias, _Float16* __restrict__ Cout)
{
  __shared__ __align__(16) _Float16 aL[64][72];
  __shared__ __align__(16) _Float16 wL[256][72];
  const int tid  = threadIdx.x;
  const int wave = tid >> 6;
  const int lane = tid & 63;
  const int lr   = lane & 15;
  const int kg   = lane >> 4;
  const size_t m0 = (size_t)blockIdx.x * 64;

  float4v acc[4][4];
  #pragma unroll
  for (int a=0;a<4;a++)
    #pragma unroll
    for (int b=0;b<4;b++)
      acc[a][b] = float4v{0.f,0.f,0.f,0.f};

  for (int kc = 0; kc < KIN; kc += 64) {
    if constexpr (__is_same(AT, float)) {
      #pragma unroll
      for (int q=0;q<4;q++){
        int fi = tid + q*256;
        int r = fi >> 4, c4 = (fi & 15)*4;
        *reinterpret_cast<half4v*>(&aL[r][c4]) = ld4h(&A[(m0+(size_t)r)*KIN + kc + c4]);
      }
    } else {
      #pragma unroll
      for (int q=0;q<2;q++){
        int fi = tid + q*256;
        int r = fi >> 3, c8 = (fi & 7)*8;
        *reinterpret_cast<half8v*>(&aL[r][c8]) =
            *reinterpret_cast<const half8v*>(&A[(m0+(size_t)r)*KIN + kc + c8]);
      }
    }
    #pragma unroll
    for (int q=0;q<8;q++){
      int fi = tid + q*256;
      int n = fi >> 3, c8 = (fi & 7)*8;
      *reinterpret_cast<half8v*>(&wL[n][c8]) =
          *reinterpret_cast<const half8v*>(&W16[(size_t)n*KIN + kc + c8]);
    }
    __syncthreads();
    #pragma unroll
    for (int ks=0; ks<64; ks+=32){
      half8v af[4], bf[4];
      #pragma unroll
      for (int rt=0;rt<4;rt++)
        af[rt] = *reinterpret_cast<const half8v*>(&aL[rt*16+lr][ks + kg*8]);
      #pragma unroll
      for (int ct=0;ct<4;ct++)
        bf[ct] = *reinterpret_cast<const half8v*>(&wL[wave*64 + ct*16 + lr][ks + kg*8]);
      #pragma unroll
      for (int rt=0;rt<4;rt++)
        #pragma unroll
        for (int ct=0;ct<4;ct++)
          acc[rt][ct] = __builtin_amdgcn_mfma_f32_16x16x32_f16(af[rt], bf[ct], acc[rt][ct], 0,0,0);
    }
    __syncthreads();
  }
  #pragma unroll
  for (int ct=0;ct<4;ct++){
    const int col = wave*64 + ct*16 + lr;
    const float bv = bias[col];
    #pragma unroll
    for (int rt=0;rt<4;rt++){
      const size_t rbase = m0 + rt*16 + kg*4;
      #pragma unroll
      for (int i=0;i<4;i++)
        Cout[(rbase+(size_t)i)*NG + col] = (_Float16)(acc[rt][ct][i] + bv);
    }
  }
}

// ---------------- LDS-weight packed-fp16 LSTM scan ----------------
// Block: 256 thr / 4 waves, NB=4 batch rows. Weights staged ONCE in LDS
// (32KB, transposed [kk][col] half8 units) -> amortized over 4 rows/step;
// no register-residency fight (r2-r8: allocator refuses 32 weight VGPRs).
// Phase1: lane = gate col c (wave=gate); per kk: 1 w-b128 + 4 h-broadcast-b128
// + 16 v_pk_fma_f16 (fp16 accum, 4 chains/row of len 8). acts f32 in LDS.
// Phase2: lane = (row=wave, j); c/h update replicate-free; h -> hlds.
// 2 barriers/step. xg: 4 coalesced b16 loads/lane/step, depth-2 named ring.
template<int MODE>
__global__ __launch_bounds__(256, 1)
void lstm_scan_lds(const _Float16* __restrict__ xgPool,  // fwd 0, rev +BB*TT*NG
                   const _Float16* __restrict__ whhTP,   // fwd 0, rev +16384
                   int nF,
                   _Float16* __restrict__ x1out, float* __restrict__ hfin)
{
  const int l = threadIdx.x;          // phase1: gate col c = l
  const int w = l >> 6;               // wave id = gate (ph1) = row (ph2)
  const int j = l & 63;
  const bool rev = (int)blockIdx.x >= nF;
  const int bblk = rev ? ((int)blockIdx.x - nF) : (int)blockIdx.x;
  const int b0 = bblk * 4;
  const _Float16* xg   = xgPool + (rev ? (size_t)BB*TT*NG : 0);
  const _Float16* whhT = whhTP  + (rev ? (size_t)16384 : 0);

  __shared__ __align__(16) _Float16 wlds[16384];    // 32KB [kk][col] half8 units
  __shared__ __align__(16) float    acts[4][256];   // 4KB
  __shared__ __align__(16) _Float16 hlds[4][64];    // 512B

  // stage weights: 8 coalesced rounds of 16B/thread
  #pragma unroll
  for (int q=0;q<8;q++){
    const int u = q*256 + l;
    *reinterpret_cast<half8v*>(&wlds[u*8]) =
        *reinterpret_cast<const half8v*>(&whhT[(size_t)u*8]);
  }
  if (l < 128) ((unsigned*)hlds)[l] = 0u;
  float c = 0.f, h_last = 0.f;
  __syncthreads();

  const int t0 = rev ? (TT-1) : 0;
  const ptrdiff_t dstep = rev ? -(ptrdiff_t)NG : (ptrdiff_t)NG;
  const _Float16* p0 = xg + ((size_t)(b0+0)*TT + t0)*NG + l;
  const _Float16* p1 = xg + ((size_t)(b0+1)*TT + t0)*NG + l;
  const _Float16* p2 = xg + ((size_t)(b0+2)*TT + t0)*NG + l;
  const _Float16* p3 = xg + ((size_t)(b0+3)*TT + t0)*NG + l;

  half4v sA, sB;   // ring slots [row]
  sA[0]=*p0; sA[1]=*p1; sA[2]=*p2; sA[3]=*p3;
  p0+=dstep; p1+=dstep; p2+=dstep; p3+=dstep;
  sB[0]=*p0; sB[1]=*p1; sB[2]=*p2; sB[3]=*p3;
  p0+=dstep; p1+=dstep; p2+=dstep; p3+=dstep;

#define SCAN_STEP(tt_, S_) do {                                               \
    const int tt = (tt_);                                                     \
    const int t  = rev ? (TT-1-tt) : tt;                                      \
    const float xr0=(float)S_[0], xr1=(float)S_[1];                           \
    const float xr2=(float)S_[2], xr3=(float)S_[3];                           \
    if (tt+2 < TT){                                                           \
      S_[0]=*p0; S_[1]=*p1; S_[2]=*p2; S_[3]=*p3;                             \
      p0+=dstep; p1+=dstep; p2+=dstep; p3+=dstep;                             \
    }                                                                         \
    half2v a00={0,0},a01={0,0},a02={0,0},a03={0,0};                           \
    half2v a10={0,0},a11={0,0},a12={0,0},a13={0,0};                           \
    half2v a20={0,0},a21={0,0},a22={0,0},a23={0,0};                           \
    half2v a30={0,0},a31={0,0},a32={0,0},a33={0,0};                           \
    _Pragma("unroll")                                                         \
    for (int kk=0;kk<8;kk++){                                                 \
      const half8v w8 = *reinterpret_cast<const half8v*>(&wlds[(kk*256+l)*8]);\
      const half8v h0 = *reinterpret_cast<const half8v*>(&hlds[0][kk*8]);     \
      const half8v h1 = *reinterpret_cast<const half8v*>(&hlds[1][kk*8]);     \
      const half8v h2 = *reinterpret_cast<const half8v*>(&hlds[2][kk*8]);     \
      const half8v h3 = *reinterpret_cast<const half8v*>(&hlds[3][kk*8]);     \
      a00=pkfma_(SV2(w8,0),SV2(h0,0),a00); a01=pkfma_(SV2(w8,1),SV2(h0,1),a01);\
      a02=pkfma_(SV2(w8,2),SV2(h0,2),a02); a03=pkfma_(SV2(w8,3),SV2(h0,3),a03);\
      a10=pkfma_(SV2(w8,0),SV2(h1,0),a10); a11=pkfma_(SV2(w8,1),SV2(h1,1),a11);\
      a12=pkfma_(SV2(w8,2),SV2(h1,2),a12); a13=pkfma_(SV2(w8,3),SV2(h1,3),a13);\
      a20=pkfma_(SV2(w8,0),SV2(h2,0),a20); a21=pkfma_(SV2(w8,1),SV2(h2,1),a21);\
      a22=pkfma_(SV2(w8,2),SV2(h2,2),a22); a23=pkfma_(SV2(w8,3),SV2(h2,3),a23);\
      a30=pkfma_(SV2(w8,0),SV2(h3,0),a30); a31=pkfma_(SV2(w8,1),SV2(h3,1),a31);\
      a32=pkfma_(SV2(w8,2),SV2(h3,2),a32); a33=pkfma_(SV2(w8,3),SV2(h3,3),a33);\
    }                                                                         \
    const half2v s0 = (a00+a01)+(a02+a03);                                    \
    const half2v s1 = (a10+a11)+(a12+a13);                                    \
    const half2v s2 = (a20+a21)+(a22+a23);                                    \
    const half2v s3 = (a30+a31)+(a32+a33);                                    \
    const float pre0 = xr0 + (float)s0[0] + (float)s0[1];                     \
    const float pre1 = xr1 + (float)s1[0] + (float)s1[1];                     \
    const float pre2 = xr2 + (float)s2[0] + (float)s2[1];                     \
    const float pre3 = xr3 + (float)s3[0] + (float)s3[1];                     \
    if (w == 2){                                                              \
      acts[0][l]=th_(pre0); acts[1][l]=th_(pre1);                             \
      acts[2][l]=th_(pre2); acts[3][l]=th_(pre3);                             \
    } else {                                                                  \
      acts[0][l]=sig_(pre0); acts[1][l]=sig_(pre1);                           \
      acts[2][l]=sig_(pre2); acts[3][l]=sig_(pre3);                           \
    }                                                                         \
    __syncthreads();                                                          \
    const float iv = acts[w][j];                                              \
    const float fv = acts[w][64+j];                                           \
    const float gv = acts[w][128+j];                                          \
    const float ov = acts[w][192+j];                                          \
    c = fv*c + iv*gv;                                                         \
    const float h = ov * th_(c);                                              \
    h_last = h;                                                               \
    hlds[w][j] = (_Float16)h;                                                 \
    if constexpr (MODE==0)                                                    \
      x1out[((size_t)(b0+w)*TT + t)*128 + (rev ? 64 : 0) + j] = (_Float16)h;  \
    __syncthreads();                                                          \
  } while(0)

  for (int tb=0; tb<TT; tb+=2){
    SCAN_STEP(tb,   sA);
    SCAN_STEP(tb+1, sB);
  }
#undef SCAN_STEP

  if constexpr (MODE==1)
    hfin[(size_t)(b0+w)*64 + j] = h_last;
}

// Layer-1 reverse collapses to ONE step from zero state on x1[:,T-1]; fuse with FC.
__global__ __launch_bounds__(256)
void final_fuse(const _Float16* __restrict__ x1, const float* __restrict__ w_ih,
                const float* __restrict__ bvec, const float* __restrict__ hfin,
                const float* __restrict__ fcw, const float* __restrict__ fcb,
                float* __restrict__ out)
{
  const int b = blockIdx.x, tid = threadIdx.x;
  __shared__ float xs[128];
  __shared__ float act[256];
  __shared__ float hall[128];
  if (tid < 128) xs[tid] = (float)x1[((size_t)b*TT + (TT-1))*128 + tid];
  __syncthreads();
  float a = bvec[tid];
  #pragma unroll
  for (int kk=0;kk<32;kk++){
    float4v wv = *reinterpret_cast<const float4v*>(&w_ih[(size_t)tid*128 + kk*4]);
    a += wv[0]*xs[kk*4] + wv[1]*xs[kk*4+1] + wv[2]*xs[kk*4+2] + wv[3]*xs[kk*4+3];
  }
  const int grp = tid>>6;
  act[tid] = (grp==2) ? th_(a) : sig_(a);
  __syncthreads();
  if (tid < 64) {
    float c = act[tid]*act[128+tid];        // c = i*g (c0 = 0)
    float h = act[192+tid]*th_(c);          // h = o*tanh(c)
    hall[64+tid] = h;
    hall[tid] = hfin[(size_t)b*64 + tid];
  }
  __syncthreads();
  if (tid < 3) {
    float acc2 = fcb[tid];
    for (int k=0;k<128;k++) acc2 += fcw[(size_t)tid*128 + k]*hall[k];
    out[(size_t)b*3 + tid] = acc2;
  }
}

extern "C" void kernel_launch(void* const* d_in, const int* in_sizes, int n_in,
                              void* d_out, int out_size, void* d_ws, size_t ws_size,
                              hipStream_t stream) {
  const float* x        = (const float*)d_in[0];
  const float* w_ih_l0f = (const float*)d_in[1];
  const float* w_hh_l0f = (const float*)d_in[2];
  const float* b_l0f    = (const float*)d_in[3];
  const float* w_ih_l0r = (const float*)d_in[4];
  const float* w_hh_l0r = (const float*)d_in[5];
  const float* b_l0r    = (const float*)d_in[6];
  const float* w_ih_l1f = (const float*)d_in[7];
  const float* w_hh_l1f = (const float*)d_in[8];
  const float* b_l1f    = (const float*)d_in[9];
  const float* w_ih_l1r = (const float*)d_in[10];
  const float* b_l1r    = (const float*)d_in[12];
  const float* fc_w     = (const float*)d_in[13];
  const float* fc_b     = (const float*)d_in[14];
  float* out = (float*)d_out;

  // workspace layout (bytes)
  const size_t XG_BYTES = (size_t)BB*TT*NG*2;      // 67,108,864 (fp16); xgF then xgR ADJACENT
  const size_t X1_BYTES = (size_t)BB*TT*128*2;     // 33,554,432
  const size_t HF_BYTES = (size_t)BB*64*4;         //    131,072
  const size_t W16_BYTES = (size_t)147456*2;       //    294,912
  if (ws_size < 2*XG_BYTES + X1_BYTES + HF_BYTES + W16_BYTES) return;
  _Float16* xgF  = (_Float16*)d_ws;
  _Float16* xgR  = (_Float16*)((char*)d_ws + XG_BYTES);   // = xgF + BB*TT*NG halves
  _Float16* x1   = (_Float16*)((char*)d_ws + 2*XG_BYTES);
  float*    hfin = (float*)   ((char*)d_ws + 2*XG_BYTES + X1_BYTES);
  _Float16* w16  = (_Float16*)((char*)d_ws + 2*XG_BYTES + X1_BYTES + HF_BYTES);
  _Float16* wih_l0f16 = w16;
  _Float16* wih_l0r16 = w16 + 32768;
  _Float16* wih_l1f16 = w16 + 65536;
  _Float16* whhT_l0f  = w16 + 98304;    // whhT_l0r = +16384 halves (adjacent)
  _Float16* whhT_l1f  = w16 + 131072;

  const int MBLK = (BB*TT)/64;  // 2048

  conv_weights<<<576, 256, 0, stream>>>(w_ih_l0f, w_ih_l0r, w_ih_l1f,
                                        w_hh_l0f, w_hh_l0r, w_hh_l1f, w16);
  // layer 0: both input GEMMs, then fused fwd+rev scan (256 blocks = 1/CU)
  gemm_xg<float><<<MBLK, 256, 0, stream>>>(x, wih_l0f16, b_l0f, xgF);
  gemm_xg<float><<<MBLK, 256, 0, stream>>>(x, wih_l0r16, b_l0r, xgR);
  lstm_scan_lds<0><<<256, 256, 0, stream>>>(xgF, whhT_l0f, 128, x1, nullptr);
  // layer 1 forward (only final h needed): 128 blocks
  gemm_xg<_Float16><<<MBLK, 256, 0, stream>>>(x1, wih_l1f16, b_l1f, xgF);
  lstm_scan_lds<1><<<128, 256, 0, stream>>>(xgF, whhT_l1f, 128, nullptr, hfin);
  // layer 1 reverse one-step + FC
  final_fuse<<<BB, 256, 0, stream>>>(x1, w_ih_l1r, b_l1r, hfin, fc_w, fc_b, out);
}

// Round 11
// 556.281 us; speedup vs baseline: 1.3432x; 1.2535x over previous
//
#include <hip/hip_runtime.h>

#define TT 256   // T
#define BB 512   // B
#define NG 256   // 4*H
#define KIN 128  // input width for both layers

typedef _Float16 half2v __attribute__((ext_vector_type(2)));
typedef _Float16 half4v __attribute__((ext_vector_type(4)));
typedef _Float16 half8v __attribute__((ext_vector_type(8)));
typedef float float4v __attribute__((ext_vector_type(4)));

__device__ __forceinline__ float sig_(float x){ return 1.f/(1.f+__expf(-x)); }
__device__ __forceinline__ float th_(float x){ return fmaf(2.f, 1.f/(1.f+__expf(-2.f*x)), -1.f); }

#define SV2(v,k) __builtin_shufflevector((v),(v), 2*(k), 2*(k)+1)

#if __has_builtin(__builtin_elementwise_fma)
__device__ __forceinline__ half2v pkfma_(half2v a, half2v b, half2v c){
  return __builtin_elementwise_fma(a, b, c);
}
#else
__device__ __forceinline__ half2v pkfma_(half2v a, half2v b, half2v c){
  return a*b + c;
}
#endif

__device__ __forceinline__ half4v ld4h(const float* p){
  float4v v = *reinterpret_cast<const float4v*>(p);
  half4v h; h[0]=(_Float16)v[0]; h[1]=(_Float16)v[1]; h[2]=(_Float16)v[2]; h[3]=(_Float16)v[3];
  return h;
}

// ---- one-shot weight conversion fp32 -> fp16 into ws pool (all row-major) ----
// halves offsets: wih_l0f 0, wih_l0r 32768, wih_l1f 65536,
//                 whh_l0f 98304, whh_l0r 114688, whh_l1f 131072  (total 147456)
__global__ __launch_bounds__(256)
void conv_weights(const float* __restrict__ s0, const float* __restrict__ s1,
                  const float* __restrict__ s2, const float* __restrict__ s3,
                  const float* __restrict__ s4, const float* __restrict__ s5,
                  _Float16* __restrict__ dst)
{
  const int bid = blockIdx.x, tid = threadIdx.x;
  const float* src; int off, idx;
  if (bid < 128)      { src=s0; off=0;      idx=bid*256+tid; }
  else if (bid < 256) { src=s1; off=32768;  idx=(bid-128)*256+tid; }
  else if (bid < 384) { src=s2; off=65536;  idx=(bid-256)*256+tid; }
  else if (bid < 448) { src=s3; off=98304;  idx=(bid-384)*256+tid; }
  else if (bid < 512) { src=s4; off=114688; idx=(bid-448)*256+tid; }
  else                { src=s5; off=131072; idx=(bid-512)*256+tid; }
  dst[off+idx] = (_Float16)src[idx];
}

// C[m][n] = sum_k A[m][k]*W[n][k] + bias[n], written fp16.
template<typename AT>
__global__ __launch_bounds__(256)
void gemm_xg(const AT* __restrict__ A, const _Float16* __restrict__ W16,
             const float* __restrict__ bias, _Float16* __restrict__ Cout)
{
  __shared__ __align__(16) _Float16 aL[64][72];
  __shared__ __align__(16) _Float16 wL[256][72];
  const int tid  = threadIdx.x;
  const int wave = tid >> 6;
  const int lane = tid & 63;
  const int lr   = lane & 15;
  const int kg   = lane >> 4;
  const size_t m0 = (size_t)blockIdx.x * 64;

  float4v acc[4][4];
  #pragma unroll
  for (int a=0;a<4;a++)
    #pragma unroll
    for (int b=0;b<4;b++)
      acc[a][b] = float4v{0.f,0.f,0.f,0.f};

  for (int kc = 0; kc < KIN; kc += 64) {
    if constexpr (__is_same(AT, float)) {
      #pragma unroll
      for (int q=0;q<4;q++){
        int fi = tid + q*256;
        int r = fi >> 4, c4 = (fi & 15)*4;
        *reinterpret_cast<half4v*>(&aL[r][c4]) = ld4h(&A[(m0+(size_t)r)*KIN + kc + c4]);
      }
    } else {
      #pragma unroll
      for (int q=0;q<2;q++){
        int fi = tid + q*256;
        int r = fi >> 3, c8 = (fi & 7)*8;
        *reinterpret_cast<half8v*>(&aL[r][c8]) =
            *reinterpret_cast<const half8v*>(&A[(m0+(size_t)r)*KIN + kc + c8]);
      }
    }
    #pragma unroll
    for (int q=0;q<8;q++){
      int fi = tid + q*256;
      int n = fi >> 3, c8 = (fi & 7)*8;
      *reinterpret_cast<half8v*>(&wL[n][c8]) =
          *reinterpret_cast<const half8v*>(&W16[(size_t)n*KIN + kc + c8]);
    }
    __syncthreads();
    #pragma unroll
    for (int ks=0; ks<64; ks+=32){
      half8v af[4], bf[4];
      #pragma unroll
      for (int rt=0;rt<4;rt++)
        af[rt] = *reinterpret_cast<const half8v*>(&aL[rt*16+lr][ks + kg*8]);
      #pragma unroll
      for (int ct=0;ct<4;ct++)
        bf[ct] = *reinterpret_cast<const half8v*>(&wL[wave*64 + ct*16 + lr][ks + kg*8]);
      #pragma unroll
      for (int rt=0;rt<4;rt++)
        #pragma unroll
        for (int ct=0;ct<4;ct++)
          acc[rt][ct] = __builtin_amdgcn_mfma_f32_16x16x32_f16(af[rt], bf[ct], acc[rt][ct], 0,0,0);
    }
    __syncthreads();
  }
  #pragma unroll
  for (int ct=0;ct<4;ct++){
    const int col = wave*64 + ct*16 + lr;
    const float bv = bias[col];
    #pragma unroll
    for (int rt=0;rt<4;rt++){
      const size_t rbase = m0 + rt*16 + kg*4;
      #pragma unroll
      for (int i=0;i<4;i++)
        Cout[(rbase+(size_t)i)*NG + col] = (_Float16)(acc[rt][ct][i] + bv);
    }
  }
}

// ---------------- r11 scan: LDS weights + XOR swizzle + NB rows + 2 blocks/CU --
// Block: 256 thr / 4 waves, NB batch rows (NB=2 layer0, NB=1 layer1), grid 512
// -> 2 blocks/CU (r10's fatal 1/CU fixed). Weights staged once in 32KB LDS,
// XOR-swizzled (byte ^= (row&7)<<4) so the stride-128B row reads hit the 8-way
// b128 floor instead of 32-way. Phase1: lane=gate-col l; per kk: 1 swizzled
// w-b128 + NB broadcast h-b128 + 4*NB pk_fma (fp16 accum, r10-validated).
// Phase2: lanes<NB*64 do c/h update. 2 barriers/step; ring depth 2 on xg.
template<int NB, int MODE>
__global__ __launch_bounds__(256, 2)
void lstm_scan_v11(const _Float16* __restrict__ xgPool,  // fwd 0, rev +BB*TT*NG
                   const _Float16* __restrict__ whhPool, // fwd 0, rev +16384
                   int nF,
                   _Float16* __restrict__ x1out, float* __restrict__ hfin)
{
  const int l = threadIdx.x;          // phase1: gate col
  const int w = l >> 6;               // gate id (phase1)
  const bool rev = (int)blockIdx.x >= nF;
  const int bblk = rev ? ((int)blockIdx.x - nF) : (int)blockIdx.x;
  const int b0 = bblk * NB;
  const _Float16* xg  = xgPool  + (rev ? (size_t)BB*TT*NG : 0);
  const _Float16* whh = whhPool + (rev ? (size_t)16384 : 0);

  __shared__ __align__(16) _Float16 wlds[16384];    // 32KB swizzled [row][128B]
  __shared__ __align__(16) float    acts[NB][256];
  __shared__ __align__(16) _Float16 hlds[NB][64];

  // stage weights: global offset = u*8 halves (fully coalesced); LDS swizzled
  #pragma unroll
  for (int q=0;q<8;q++){
    const int u = q*256 + l;
    const int row = u >> 3, k8 = u & 7;
    const int byte = (row*128 + k8*16) ^ ((row & 7) << 4);
    *reinterpret_cast<half8v*>((char*)wlds + byte) =
        *reinterpret_cast<const half8v*>(&whh[(size_t)u*8]);
  }
  if (l < NB*32) ((unsigned*)hlds)[l] = 0u;
  float c = 0.f, h_last = 0.f;
  __syncthreads();

  const int t0i = rev ? (TT-1) : 0;
  const ptrdiff_t dstep = rev ? -(ptrdiff_t)NG : (ptrdiff_t)NG;
  const _Float16* p0 = xg + ((size_t)(b0+0)*TT + t0i)*NG + l;
  const _Float16* p1 = (NB==2) ? (xg + ((size_t)(b0+1)*TT + t0i)*NG + l) : p0;

  half2v sA, sB;   // ring slots: [0]=row0, [1]=row1 (row1 dead if NB==1)
  sA[0]=*p0; sA[1]=*p1; p0+=dstep; p1+=dstep;
  sB[0]=*p0; sB[1]=*p1; p0+=dstep; p1+=dstep;

  const int aswz = (l & 7) << 4;

#define SCAN_STEP(tt_, S_) do {                                               \
    const int tt = (tt_);                                                     \
    const int t  = rev ? (TT-1-tt) : tt;                                      \
    const float xr0 = (float)S_[0];                                           \
    const float xr1 = (float)S_[1];                                           \
    if (tt+2 < TT){ S_[0]=*p0; S_[1]=*p1; p0+=dstep; p1+=dstep; }             \
    half2v a00={0,0},a01={0,0},a02={0,0},a03={0,0};                           \
    half2v a10={0,0},a11={0,0},a12={0,0},a13={0,0};                           \
    _Pragma("unroll")                                                         \
    for (int kk=0;kk<8;kk++){                                                 \
      const half8v w8 = *reinterpret_cast<const half8v*>(                     \
          (const char*)wlds + ((l*128 + kk*16) ^ aswz));                      \
      const half8v h0 = *reinterpret_cast<const half8v*>(&hlds[0][kk*8]);     \
      a00=pkfma_(SV2(w8,0),SV2(h0,0),a00);                                    \
      a01=pkfma_(SV2(w8,1),SV2(h0,1),a01);                                    \
      a02=pkfma_(SV2(w8,2),SV2(h0,2),a02);                                    \
      a03=pkfma_(SV2(w8,3),SV2(h0,3),a03);                                    \
      if constexpr (NB==2){                                                   \
        const half8v h1 = *reinterpret_cast<const half8v*>(&hlds[1][kk*8]);   \
        a10=pkfma_(SV2(w8,0),SV2(h1,0),a10);                                  \
        a11=pkfma_(SV2(w8,1),SV2(h1,1),a11);                                  \
        a12=pkfma_(SV2(w8,2),SV2(h1,2),a12);                                  \
        a13=pkfma_(SV2(w8,3),SV2(h1,3),a13);                                  \
      }                                                                       \
    }                                                                         \
    const half2v s0 = (a00+a01)+(a02+a03);                                    \
    const float pre0 = xr0 + (float)s0[0] + (float)s0[1];                     \
    if (w == 2){                                                              \
      acts[0][l] = th_(pre0);                                                 \
      if constexpr (NB==2){                                                   \
        const half2v s1 = (a10+a11)+(a12+a13);                                \
        acts[1][l] = th_(xr1 + (float)s1[0] + (float)s1[1]);                  \
      }                                                                       \
    } else {                                                                  \
      acts[0][l] = sig_(pre0);                                                \
      if constexpr (NB==2){                                                   \
        const half2v s1 = (a10+a11)+(a12+a13);                                \
        acts[1][l] = sig_(xr1 + (float)s1[0] + (float)s1[1]);                 \
      }                                                                       \
    }                                                                         \
    __syncthreads();                                                          \
    if (l < NB*64){                                                           \
      const int r  = (NB==2) ? (l>>6) : 0;                                    \
      const int jj = l & 63;                                                  \
      const float iv = acts[r][jj];                                           \
      const float fv = acts[r][64+jj];                                        \
      const float gv = acts[r][128+jj];                                       \
      const float ov = acts[r][192+jj];                                       \
      c = fv*c + iv*gv;                                                       \
      const float h = ov * th_(c);                                            \
      h_last = h;                                                             \
      hlds[r][jj] = (_Float16)h;                                              \
      if constexpr (MODE==0)                                                  \
        x1out[((size_t)(b0+r)*TT + t)*128 + (rev ? 64 : 0) + jj] = (_Float16)h;\
    }                                                                         \
    __syncthreads();                                                          \
  } while(0)

  for (int tb=0; tb<TT; tb+=2){
    SCAN_STEP(tb,   sA);
    SCAN_STEP(tb+1, sB);
  }
#undef SCAN_STEP

  if constexpr (MODE==1){
    if (l < NB*64){
      const int r  = (NB==2) ? (l>>6) : 0;
      hfin[(size_t)(b0+r)*64 + (l & 63)] = h_last;
    }
  }
}

// Layer-1 reverse collapses to ONE step from zero state on x1[:,T-1]; fuse with FC.
__global__ __launch_bounds__(256)
void final_fuse(const _Float16* __restrict__ x1, const float* __restrict__ w_ih,
                const float* __restrict__ bvec, const float* __restrict__ hfin,
                const float* __restrict__ fcw, const float* __restrict__ fcb,
                float* __restrict__ out)
{
  const int b = blockIdx.x, tid = threadIdx.x;
  __shared__ float xs[128];
  __shared__ float act[256];
  __shared__ float hall[128];
  if (tid < 128) xs[tid] = (float)x1[((size_t)b*TT + (TT-1))*128 + tid];
  __syncthreads();
  float a = bvec[tid];
  #pragma unroll
  for (int kk=0;kk<32;kk++){
    float4v wv = *reinterpret_cast<const float4v*>(&w_ih[(size_t)tid*128 + kk*4]);
    a += wv[0]*xs[kk*4] + wv[1]*xs[kk*4+1] + wv[2]*xs[kk*4+2] + wv[3]*xs[kk*4+3];
  }
  const int grp = tid>>6;
  act[tid] = (grp==2) ? th_(a) : sig_(a);
  __syncthreads();
  if (tid < 64) {
    float c = act[tid]*act[128+tid];        // c = i*g (c0 = 0)
    float h = act[192+tid]*th_(c);          // h = o*tanh(c)
    hall[64+tid] = h;
    hall[tid] = hfin[(size_t)b*64 + tid];
  }
  __syncthreads();
  if (tid < 3) {
    float acc2 = fcb[tid];
    for (int k=0;k<128;k++) acc2 += fcw[(size_t)tid*128 + k]*hall[k];
    out[(size_t)b*3 + tid] = acc2;
  }
}

extern "C" void kernel_launch(void* const* d_in, const int* in_sizes, int n_in,
                              void* d_out, int out_size, void* d_ws, size_t ws_size,
                              hipStream_t stream) {
  const float* x        = (const float*)d_in[0];
  const float* w_ih_l0f = (const float*)d_in[1];
  const float* w_hh_l0f = (const float*)d_in[2];
  const float* b_l0f    = (const float*)d_in[3];
  const float* w_ih_l0r = (const float*)d_in[4];
  const float* w_hh_l0r = (const float*)d_in[5];
  const float* b_l0r    = (const float*)d_in[6];
  const float* w_ih_l1f = (const float*)d_in[7];
  const float* w_hh_l1f = (const float*)d_in[8];
  const float* b_l1f    = (const float*)d_in[9];
  const float* w_ih_l1r = (const float*)d_in[10];
  const float* b_l1r    = (const float*)d_in[12];
  const float* fc_w     = (const float*)d_in[13];
  const float* fc_b     = (const float*)d_in[14];
  float* out = (float*)d_out;

  // workspace layout (bytes)
  const size_t XG_BYTES = (size_t)BB*TT*NG*2;      // 67,108,864 (fp16); xgF then xgR ADJACENT
  const size_t X1_BYTES = (size_t)BB*TT*128*2;     // 33,554,432
  const size_t HF_BYTES = (size_t)BB*64*4;         //    131,072
  const size_t W16_BYTES = (size_t)147456*2;       //    294,912
  if (ws_size < 2*XG_BYTES + X1_BYTES + HF_BYTES + W16_BYTES) return;
  _Float16* xgF  = (_Float16*)d_ws;
  _Float16* xgR  = (_Float16*)((char*)d_ws + XG_BYTES);   // = xgF + BB*TT*NG halves
  _Float16* x1   = (_Float16*)((char*)d_ws + 2*XG_BYTES);
  float*    hfin = (float*)   ((char*)d_ws + 2*XG_BYTES + X1_BYTES);
  _Float16* w16  = (_Float16*)((char*)d_ws + 2*XG_BYTES + X1_BYTES + HF_BYTES);
  _Float16* wih_l0f16 = w16;
  _Float16* wih_l0r16 = w16 + 32768;
  _Float16* wih_l1f16 = w16 + 65536;
  _Float16* whh_l0f16 = w16 + 98304;    // whh_l0r16 = +16384 halves (adjacent)
  _Float16* whh_l1f16 = w16 + 131072;

  const int MBLK = (BB*TT)/64;  // 2048

  conv_weights<<<576, 256, 0, stream>>>(w_ih_l0f, w_ih_l0r, w_ih_l1f,
                                        w_hh_l0f, w_hh_l0r, w_hh_l1f, w16);
  // layer 0: both input GEMMs, then fused fwd+rev scan (512 blocks = 2/CU, NB=2)
  gemm_xg<float><<<MBLK, 256, 0, stream>>>(x, wih_l0f16, b_l0f, xgF);
  gemm_xg<float><<<MBLK, 256, 0, stream>>>(x, wih_l0r16, b_l0r, xgR);
  lstm_scan_v11<2,0><<<512, 256, 0, stream>>>(xgF, whh_l0f16, 256, x1, nullptr);
  // layer 1 forward (only final h needed): 512 blocks, NB=1 (2/CU)
  gemm_xg<_Float16><<<MBLK, 256, 0, stream>>>(x1, wih_l1f16, b_l1f, xgF);
  lstm_scan_v11<1,1><<<512, 256, 0, stream>>>(xgF, whh_l1f16, 512, nullptr, hfin);
  // layer 1 reverse one-step + FC
  final_fuse<<<BB, 256, 0, stream>>>(x1, w_ih_l1r, b_l1r, hfin, fc_w, fc_b, out);
}